// Round 1
// baseline (746.661 us; speedup 1.0000x reference)
//
#include <hip/hip_runtime.h>

// SpearmanCorrelationLoss on MI355X (gfx950)
//
// Key reduction: double-argsort ranks are always a permutation of 1..N, so
// per-column mean/var of ranks are exact constants. Only Sum(rank_p * rank_t)
// per column is needed:
//   corr_c = (S/N - 8192.5^2) / ((N^2-1)/12 + 2*EPS),  out = -mean_c(corr_c)
//
// Ranks via: sort u32 order-keys of a column in LDS (bitonic), then
// lower_bound binary search per element. Ties get equal (lower_bound) ranks
// instead of stable-index ranks; per-tie error on the final scalar is
// ~8.7e-11 (<< 4.4e-6 threshold), with ~10 ties/column expected.

#define N_ROWS 16384
#define N_COLS 512
#define NT 1024
#define PER_T (N_ROWS / NT)   // 16 elements per thread

__device__ __forceinline__ unsigned f2key(float x) {
    // order-preserving map fp32 -> u32 (no NaNs in input)
    unsigned u = __float_as_uint(x);
    return (u & 0x80000000u) ? ~u : (u | 0x80000000u);
}

__device__ __forceinline__ void bitonic_sort(unsigned* sh, int tid) {
    for (int k = 2; k <= N_ROWS; k <<= 1) {
        for (int j = k >> 1; j > 0; j >>= 1) {
            __syncthreads();
            #pragma unroll
            for (int p = 0; p < PER_T / 2; ++p) {
                int w = tid + p * NT;              // pair index 0..N/2-1
                int i = w + (w & ~(j - 1));        // insert 0 at bit log2(j)
                unsigned a = sh[i];
                unsigned b = sh[i + j];
                bool asc = ((i & k) == 0);
                unsigned mn = a < b ? a : b;
                unsigned mx = a < b ? b : a;
                sh[i]     = asc ? mn : mx;
                sh[i + j] = asc ? mx : mn;
            }
        }
    }
    __syncthreads();
}

// lower_bound over sorted sh[0..N_ROWS-1]: returns #{elements < k}
__device__ __forceinline__ int lb_search(const unsigned* sh, unsigned k) {
    int lo = 0;
    #pragma unroll
    for (int st = N_ROWS / 2; st > 0; st >>= 1) {
        if (sh[lo + st - 1] < k) lo += st;
    }
    if (sh[lo] < k) ++lo;   // extend from [0, N-1] to [0, N]
    return lo;
}

__global__ __launch_bounds__(NT, 4)
void spearman_col_kernel(const float* __restrict__ pred,
                         const float* __restrict__ target,
                         double* __restrict__ col_corr) {
    __shared__ unsigned sh[N_ROWS];   // 64 KB
    const int col = blockIdx.x;
    const int tid = threadIdx.x;

    unsigned keys[PER_T];
    unsigned short rp[PER_T];         // lower-bound rank (0-based) of pred elems

    // ---------- phase 1: pred ----------
    #pragma unroll
    for (int s = 0; s < PER_T; ++s) {
        int e = tid + s * NT;
        unsigned k = f2key(pred[(size_t)e * N_COLS + col]);
        keys[s] = k;
        sh[e] = k;
    }
    bitonic_sort(sh, tid);
    #pragma unroll
    for (int s = 0; s < PER_T; ++s) {
        rp[s] = (unsigned short)lb_search(sh, keys[s]);
    }
    __syncthreads();   // everyone done probing before LDS is overwritten

    // ---------- phase 2: target ----------
    #pragma unroll
    for (int s = 0; s < PER_T; ++s) {
        int e = tid + s * NT;
        unsigned k = f2key(target[(size_t)e * N_COLS + col]);
        keys[s] = k;
        sh[e] = k;
    }
    bitonic_sort(sh, tid);

    unsigned long long acc = 0;
    #pragma unroll
    for (int s = 0; s < PER_T; ++s) {
        int rt = lb_search(sh, keys[s]);
        acc += (unsigned long long)(rp[s] + 1) * (unsigned long long)(rt + 1);
    }
    __syncthreads();   // done reading sorted keys; reuse LDS for reduction

    // ---------- block reduction of acc (u64, exact) ----------
    unsigned long long* red = (unsigned long long*)sh;  // 8 KB of the 64 KB
    red[tid] = acc;
    __syncthreads();
    for (int off = NT / 2; off > 0; off >>= 1) {
        if (tid < off) red[tid] += red[tid + off];
        __syncthreads();
    }

    if (tid == 0) {
        double S = (double)red[0];                      // exact (< 2^53)
        double cov = S / (double)N_ROWS - 67117056.25;  // mean^2 = 8192.5^2
        double denom = 22369621.25 + 2e-6;              // (N^2-1)/12 + 2*EPS
        col_corr[col] = cov / denom;
    }
}

__global__ void finalize_kernel(const double* __restrict__ col_corr,
                                float* __restrict__ out) {
    __shared__ double red[N_COLS];
    int t = threadIdx.x;
    red[t] = col_corr[t];
    __syncthreads();
    for (int off = N_COLS / 2; off > 0; off >>= 1) {
        if (t < off) red[t] += red[t + off];
        __syncthreads();
    }
    if (t == 0) out[0] = (float)(-red[0] / (double)N_COLS);
}

extern "C" void kernel_launch(void* const* d_in, const int* in_sizes, int n_in,
                              void* d_out, int out_size, void* d_ws, size_t ws_size,
                              hipStream_t stream) {
    const float* pred   = (const float*)d_in[0];
    const float* target = (const float*)d_in[1];
    float* out = (float*)d_out;
    double* col_corr = (double*)d_ws;   // 512 * 8 B = 4 KB of workspace

    spearman_col_kernel<<<N_COLS, NT, 0, stream>>>(pred, target, col_corr);
    finalize_kernel<<<1, N_COLS, 0, stream>>>(col_corr, out);
}

// Round 2
// 433.107 us; speedup vs baseline: 1.7240x; 1.7240x over previous
//
#include <hip/hip_runtime.h>

// SpearmanCorrelationLoss on MI355X (gfx950) — R2
//
// Math: ranks are a permutation of 1..N per column, so mean/var are exact
// constants; only S = Sum(rank_p * rank_t) per column is needed:
//   corr_c = (S/N - 8192.5^2) / ((N^2-1)/12 + 2*EPS),  out = -mean_c(corr_c)
//
// R2 changes vs R1 (which was LDS-pipe bound: 36% of cycles were bank-conflict
// stalls, 105 all-scalar bitonic passes):
//  - register-blocked bitonic: 16-elem in-register build network + in-register
//    j<=8 passes per merge stage; only 55 cross passes (j>=16) touch LDS,
//    vectorized b128 (uint4).
//  - XOR bank swizzle on 16B chunks: addr = c ^ ((c>>2)&7). Spreads the
//    register-phase (chunks 4t+m) and j=16 patterns over all 32 banks.
//  - pre-transpose inputs in workspace -> coalesced float4 column loads
//    (fallback to strided loads if ws too small).

#define N_ROWS 16384
#define N_COLS 512
#define NT 1024
#define PT 16    // elements per thread

__device__ __forceinline__ unsigned f2key(float x) {
    unsigned u = __float_as_uint(x);
    return (u & 0x80000000u) ? ~u : (u | 0x80000000u);
}

// 16B-chunk XOR swizzle: bijective, keeps uint4 alignment
__device__ __forceinline__ int swz(int c) { return c ^ ((c >> 2) & 7); }
// swizzled scalar element address
__device__ __forceinline__ int eadr(int i) { return (swz(i >> 2) << 2) | (i & 3); }

__device__ __forceinline__ void ce(unsigned& a, unsigned& b, bool asc) {
    unsigned mn = a < b ? a : b;
    unsigned mx = a < b ? b : a;
    a = asc ? mn : mx;
    b = asc ? mx : mn;
}

__device__ __forceinline__ void ce4(uint4& a, uint4& b, bool asc) {
    ce(a.x, b.x, asc); ce(a.y, b.y, asc); ce(a.z, b.z, asc); ce(a.w, b.w, asc);
}

// lower_bound count of {elements < key} over swizzled sorted sh[0..N-1]
__device__ __forceinline__ int lb_search(const unsigned* sh, unsigned key) {
    int lo = 0;
    #pragma unroll
    for (int st = N_ROWS / 2; st > 0; st >>= 1) {
        if (sh[eadr(lo + st - 1)] < key) lo += st;
    }
    if (sh[eadr(lo)] < key) ++lo;
    return lo;
}

template <int TRANSPOSED>
__global__ __launch_bounds__(NT, 4)
void spearman_col_kernel(const float* __restrict__ A, const float* __restrict__ B,
                         double* __restrict__ col_corr) {
    __shared__ __align__(16) unsigned sh[N_ROWS];   // 64 KB
    uint4* sh4 = (uint4*)sh;
    const int col = blockIdx.x;
    const int tid = threadIdx.x;

    unsigned rp2[PT / 2];            // packed u16 pred ranks (0-based)
    unsigned long long acc = 0;

    for (int phase = 0; phase < 2; ++phase) {
        const float* src = (phase == 0) ? A : B;

        // ---- load own 16 consecutive elements ----
        unsigned v[PT];
        if (TRANSPOSED) {
            const float4* colp = (const float4*)(src + (size_t)col * N_ROWS + tid * PT);
            #pragma unroll
            for (int m = 0; m < 4; ++m) {
                float4 f = colp[m];
                v[4*m+0] = f2key(f.x); v[4*m+1] = f2key(f.y);
                v[4*m+2] = f2key(f.z); v[4*m+3] = f2key(f.w);
            }
        } else {
            #pragma unroll
            for (int s = 0; s < PT; ++s)
                v[s] = f2key(src[(size_t)(tid * PT + s) * N_COLS + col]);
        }

        // ---- in-register 16-element bitonic network ----
        // run base = 16*tid; asc iff (base & 16)==0 iff tid even
        {
            const bool dasc = ((tid & 1) == 0);
            #pragma unroll
            for (int kk = 2; kk <= 16; kk <<= 1) {
                #pragma unroll
                for (int jj = kk >> 1; jj > 0; jj >>= 1) {
                    #pragma unroll
                    for (int w = 0; w < 8; ++w) {
                        int i = w + (w & ~(jj - 1));
                        ce(v[i], v[i + jj], ((i & kk) == 0) == dasc);
                    }
                }
            }
        }

        __syncthreads();   // protect previous phase's LDS readers
        #pragma unroll
        for (int m = 0; m < 4; ++m)
            sh4[swz(tid * 4 + m)] = make_uint4(v[4*m], v[4*m+1], v[4*m+2], v[4*m+3]);

        // ---- merge stages k = 32 .. 16384 ----
        for (int k = 32; k <= N_ROWS; k <<= 1) {
            for (int j = k >> 1; j >= PT; j >>= 1) {
                __syncthreads();
                #pragma unroll
                for (int g = 0; g < 2; ++g) {
                    int w0 = (tid + g * NT) * 4;        // 4 consecutive pairs
                    int i0 = w0 + (w0 & ~(j - 1));      // 4-aligned, j>=16
                    int ca = swz(i0 >> 2), cb = swz((i0 + j) >> 2);
                    uint4 a = sh4[ca];
                    uint4 b = sh4[cb];
                    ce4(a, b, (i0 & k) == 0);
                    sh4[ca] = a;
                    sh4[cb] = b;
                }
            }
            // in-register j = 8,4,2,1 on own 16 consecutive elements
            __syncthreads();
            {
                #pragma unroll
                for (int m = 0; m < 4; ++m) {
                    uint4 t4 = sh4[swz(tid * 4 + m)];
                    v[4*m+0] = t4.x; v[4*m+1] = t4.y; v[4*m+2] = t4.z; v[4*m+3] = t4.w;
                }
                const bool asc = (((tid * PT) & k) == 0);  // uniform over the 16
                #pragma unroll
                for (int jj = 8; jj > 0; jj >>= 1) {
                    #pragma unroll
                    for (int w = 0; w < 8; ++w) {
                        int i = w + (w & ~(jj - 1));
                        ce(v[i], v[i + jj], asc);
                    }
                }
                #pragma unroll
                for (int m = 0; m < 4; ++m)
                    sh4[swz(tid * 4 + m)] = make_uint4(v[4*m], v[4*m+1], v[4*m+2], v[4*m+3]);
            }
        }
        __syncthreads();   // sorted array visible to all

        // ---- re-read own original keys (L2-hot) and rank-search ----
        unsigned kx[PT];
        if (TRANSPOSED) {
            const float4* colp = (const float4*)(src + (size_t)col * N_ROWS + tid * PT);
            #pragma unroll
            for (int m = 0; m < 4; ++m) {
                float4 f = colp[m];
                kx[4*m+0] = f2key(f.x); kx[4*m+1] = f2key(f.y);
                kx[4*m+2] = f2key(f.z); kx[4*m+3] = f2key(f.w);
            }
        } else {
            #pragma unroll
            for (int s = 0; s < PT; ++s)
                kx[s] = f2key(src[(size_t)(tid * PT + s) * N_COLS + col]);
        }

        if (phase == 0) {
            #pragma unroll
            for (int s = 0; s < PT; s += 2) {
                unsigned r0 = (unsigned)lb_search(sh, kx[s]);
                unsigned r1 = (unsigned)lb_search(sh, kx[s + 1]);
                rp2[s / 2] = r0 | (r1 << 16);
            }
        } else {
            #pragma unroll
            for (int s = 0; s < PT; ++s) {
                int rt = lb_search(sh, kx[s]);
                unsigned rpv = (rp2[s / 2] >> ((s & 1) * 16)) & 0xFFFFu;
                acc += (unsigned long long)(rpv + 1) * (unsigned long long)(rt + 1);
            }
        }
    }

    // ---- exact u64 block reduction ----
    __syncthreads();
    unsigned long long* red = (unsigned long long*)sh;
    red[tid] = acc;
    __syncthreads();
    for (int off = NT / 2; off > 0; off >>= 1) {
        if (tid < off) red[tid] += red[tid + off];
        __syncthreads();
    }

    if (tid == 0) {
        double S = (double)red[0];                      // exact (< 2^53)
        double cov = S / (double)N_ROWS - 67117056.25;  // 8192.5^2
        double denom = 22369621.25 + 2e-6;              // (N^2-1)/12 + 2*EPS
        col_corr[col] = cov / denom;
    }
}

// 64x64 tile transpose: in [16384,512] row-major -> out [512,16384]
__global__ __launch_bounds__(256)
void transpose_kernel(const float* __restrict__ in0, const float* __restrict__ in1,
                      float* __restrict__ out0, float* __restrict__ out1) {
    __shared__ float tile[64][65];
    const float* in  = blockIdx.z ? in1 : in0;
    float* out       = blockIdx.z ? out1 : out0;
    const int r0 = blockIdx.x * 64;
    const int c0 = blockIdx.y * 64;
    const int t = threadIdx.x;
    const int cg = (t & 15) * 4;
    const int rr = t >> 4;
    #pragma unroll
    for (int it = 0; it < 4; ++it) {
        int r = rr + it * 16;
        float4 f = *(const float4*)&in[(size_t)(r0 + r) * N_COLS + c0 + cg];
        tile[r][cg + 0] = f.x; tile[r][cg + 1] = f.y;
        tile[r][cg + 2] = f.z; tile[r][cg + 3] = f.w;
    }
    __syncthreads();
    const int rg = (t & 15) * 4;
    const int cc = t >> 4;
    #pragma unroll
    for (int it = 0; it < 4; ++it) {
        int c = cc + it * 16;
        float4 f;
        f.x = tile[rg + 0][c]; f.y = tile[rg + 1][c];
        f.z = tile[rg + 2][c]; f.w = tile[rg + 3][c];
        *(float4*)&out[(size_t)(c0 + c) * N_ROWS + r0 + rg] = f;
    }
}

__global__ void finalize_kernel(const double* __restrict__ col_corr,
                                float* __restrict__ out) {
    __shared__ double red[N_COLS];
    int t = threadIdx.x;
    red[t] = col_corr[t];
    __syncthreads();
    for (int off = N_COLS / 2; off > 0; off >>= 1) {
        if (t < off) red[t] += red[t + off];
        __syncthreads();
    }
    if (t == 0) out[0] = (float)(-red[0] / (double)N_COLS);
}

extern "C" void kernel_launch(void* const* d_in, const int* in_sizes, int n_in,
                              void* d_out, int out_size, void* d_ws, size_t ws_size,
                              hipStream_t stream) {
    const float* pred   = (const float*)d_in[0];
    const float* target = (const float*)d_in[1];
    float* out = (float*)d_out;

    const size_t mat_bytes = (size_t)N_ROWS * N_COLS * sizeof(float);
    double* col_corr = (double*)d_ws;                       // 4 KB
    float* predT   = (float*)((char*)d_ws + 65536);
    float* targetT = predT + (size_t)N_ROWS * N_COLS;
    const size_t need = 65536 + 2 * mat_bytes;

    if (ws_size >= need) {
        dim3 tgrid(N_ROWS / 64, N_COLS / 64, 2);
        transpose_kernel<<<tgrid, 256, 0, stream>>>(pred, target, predT, targetT);
        spearman_col_kernel<1><<<N_COLS, NT, 0, stream>>>(predT, targetT, col_corr);
    } else {
        spearman_col_kernel<0><<<N_COLS, NT, 0, stream>>>(pred, target, col_corr);
    }
    finalize_kernel<<<1, N_COLS, 0, stream>>>(col_corr, out);
}

// Round 4
// 172.073 us; speedup vs baseline: 4.3392x; 2.5170x over previous
//
#include <hip/hip_runtime.h>

// SpearmanCorrelationLoss on MI355X (gfx950) — R4 (R3 with compile fix)
//
// Math: double-argsort ranks are a permutation of 1..N per column, so
// mean/var of ranks are exact constants; only S = Sum(rank_p*rank_t) needed:
//   corr_c = (S/N - 8192.5^2) / ((N^2-1)/12 + 2*EPS),  out = -mean_c(corr_c)
//
// Histogram ranking (ranks invariant under monotone maps): bucket =
// floor(sigmoid(1.702*x)*4096) approximates the Gaussian CDF -> near-uniform
// bucket loads (avg 4). rank(x) = prefix[b(x)] + #{y in same bucket : y < x}.
// Strict-less = lower_bound tie semantics; tie/boundary wobble error ~1e-10
// on the scalar output (threshold 4.4e-6).
// LDS: 16 KB cursors + 64 KB scattered keys = 80 KB -> 2 blocks/CU (160 KB).
//
// R4 fix: __exp2f/__fdividef aren't device-visible in this toolchain ->
// use __builtin_amdgcn_exp2f / __builtin_amdgcn_rcpf (v_exp_f32/v_rcp_f32).

#define N_ROWS 16384
#define N_COLS 512
#define NT 1024
#define PT 16            // elements per thread
#define NBINS 4096

__device__ __forceinline__ unsigned f2key(float x) {
    // order-preserving fp32 -> u32 (no NaNs in input)
    unsigned u = __float_as_uint(x);
    return (u & 0x80000000u) ? ~u : (u | 0x80000000u);
}

// monotone approx Gaussian-CDF bucket: sigma(1.702x) = 1/(1+2^(-2.4554x))
__device__ __forceinline__ int f2bucket(float f) {
    float e = __builtin_amdgcn_exp2f(-2.4554f * f);   // v_exp_f32
    float s = __builtin_amdgcn_rcpf(1.0f + e);        // v_rcp_f32
    int b = (int)(s * (float)NBINS);
    return b < 0 ? 0 : (b > NBINS - 1 ? NBINS - 1 : b);
}

template <int TRANSPOSED>
__global__ __launch_bounds__(NT, 8)
void spearman_col_kernel(const float* __restrict__ A, const float* __restrict__ B,
                         double* __restrict__ col_corr) {
    __shared__ unsigned cursor[NBINS];                   // 16 KB
    __shared__ __align__(16) unsigned keys_sh[N_ROWS];   // 64 KB
    const int col = blockIdx.x;
    const int tid = threadIdx.x;

    unsigned rp2[PT / 2];          // packed u16 pred ranks (0-based, <16384)
    unsigned long long acc = 0;

    for (int phase = 0; phase < 2; ++phase) {
        const float* src = (phase == 0) ? A : B;

        // ---- load 16 elements; compute keys + buckets in registers ----
        unsigned key[PT];
        unsigned bkt2[PT / 2];     // packed u16 buckets
        if (TRANSPOSED) {
            const float4* colp = (const float4*)(src + (size_t)col * N_ROWS);
            #pragma unroll
            for (int m = 0; m < 4; ++m) {
                float4 f = colp[tid + m * NT];   // 16B/lane, coalesced
                key[4*m+0] = f2key(f.x); key[4*m+1] = f2key(f.y);
                key[4*m+2] = f2key(f.z); key[4*m+3] = f2key(f.w);
                bkt2[2*m+0] = (unsigned)f2bucket(f.x) | ((unsigned)f2bucket(f.y) << 16);
                bkt2[2*m+1] = (unsigned)f2bucket(f.z) | ((unsigned)f2bucket(f.w) << 16);
            }
        } else {
            #pragma unroll
            for (int s = 0; s < PT; s += 2) {
                float f0 = src[(size_t)(tid + (s+0) * NT) * N_COLS + col];
                float f1 = src[(size_t)(tid + (s+1) * NT) * N_COLS + col];
                key[s]   = f2key(f0);
                key[s+1] = f2key(f1);
                bkt2[s/2] = (unsigned)f2bucket(f0) | ((unsigned)f2bucket(f1) << 16);
            }
        }

        // ---- zero histogram ----
        __syncthreads();   // previous phase's keys_sh/cursor readers done
        ((uint4*)cursor)[tid] = make_uint4(0u, 0u, 0u, 0u);
        __syncthreads();

        // ---- histogram ----
        #pragma unroll
        for (int s = 0; s < PT; ++s) {
            unsigned b = (bkt2[s/2] >> ((s & 1) * 16)) & 0xFFFFu;
            atomicAdd(&cursor[b], 1u);
        }
        __syncthreads();

        // ---- exclusive prefix sum over 4096 bins (4/thread) ----
        uint4 h = ((uint4*)cursor)[tid];
        unsigned mysum = h.x + h.y + h.z + h.w;
        keys_sh[tid] = mysum;          // scratch (keys not scattered yet)
        __syncthreads();
        for (int off = 1; off < NT; off <<= 1) {
            unsigned v = (tid >= off) ? keys_sh[tid - off] : 0u;
            __syncthreads();
            keys_sh[tid] += v;
            __syncthreads();
        }
        unsigned excl = keys_sh[tid] - mysum;
        ((uint4*)cursor)[tid] =
            make_uint4(excl, excl + h.x, excl + h.x + h.y, excl + h.x + h.y + h.z);
        __syncthreads();

        // ---- scatter keys into bucket slices ----
        #pragma unroll
        for (int s = 0; s < PT; ++s) {
            unsigned b = (bkt2[s/2] >> ((s & 1) * 16)) & 0xFFFFu;
            unsigned slot = atomicAdd(&cursor[b], 1u);
            keys_sh[slot] = key[s];
        }
        __syncthreads();   // after this: cursor[b] == P[b+1]

        // ---- rank: P[b] + strict-less count within slice ----
        #pragma unroll
        for (int s = 0; s < PT; ++s) {
            unsigned b = (bkt2[s/2] >> ((s & 1) * 16)) & 0xFFFFu;
            unsigned k = key[s];
            unsigned lo = (b == 0) ? 0u : cursor[b - 1];
            unsigned hi = cursor[b];
            unsigned r = lo;                       // P[b]
            for (unsigned j = lo; j < hi; ++j)
                r += (keys_sh[j] < k) ? 1u : 0u;
            if (phase == 0) {
                if ((s & 1) == 0) rp2[s/2] = r;
                else              rp2[s/2] |= (r << 16);
            } else {
                unsigned rp = (rp2[s/2] >> ((s & 1) * 16)) & 0xFFFFu;
                acc += (unsigned long long)(rp + 1) * (unsigned long long)(r + 1);
            }
        }
    }

    // ---- exact u64 block reduction ----
    __syncthreads();
    unsigned long long* red = (unsigned long long*)keys_sh;
    red[tid] = acc;
    __syncthreads();
    for (int off = NT / 2; off > 0; off >>= 1) {
        if (tid < off) red[tid] += red[tid + off];
        __syncthreads();
    }

    if (tid == 0) {
        double S = (double)red[0];                      // exact (< 2^53)
        double cov = S / (double)N_ROWS - 67117056.25;  // 8192.5^2
        double denom = 22369621.25 + 2e-6;              // (N^2-1)/12 + 2*EPS
        col_corr[col] = cov / denom;
    }
}

// 64x64 tile transpose: in [16384,512] row-major -> out [512,16384]
__global__ __launch_bounds__(256)
void transpose_kernel(const float* __restrict__ in0, const float* __restrict__ in1,
                      float* __restrict__ out0, float* __restrict__ out1) {
    __shared__ float tile[64][65];
    const float* in  = blockIdx.z ? in1 : in0;
    float* out       = blockIdx.z ? out1 : out0;
    const int r0 = blockIdx.x * 64;
    const int c0 = blockIdx.y * 64;
    const int t = threadIdx.x;
    const int cg = (t & 15) * 4;
    const int rr = t >> 4;
    #pragma unroll
    for (int it = 0; it < 4; ++it) {
        int r = rr + it * 16;
        float4 f = *(const float4*)&in[(size_t)(r0 + r) * N_COLS + c0 + cg];
        tile[r][cg + 0] = f.x; tile[r][cg + 1] = f.y;
        tile[r][cg + 2] = f.z; tile[r][cg + 3] = f.w;
    }
    __syncthreads();
    const int rg = (t & 15) * 4;
    const int cc = t >> 4;
    #pragma unroll
    for (int it = 0; it < 4; ++it) {
        int c = cc + it * 16;
        float4 f;
        f.x = tile[rg + 0][c]; f.y = tile[rg + 1][c];
        f.z = tile[rg + 2][c]; f.w = tile[rg + 3][c];
        *(float4*)&out[(size_t)(c0 + c) * N_ROWS + r0 + rg] = f;
    }
}

__global__ void finalize_kernel(const double* __restrict__ col_corr,
                                float* __restrict__ out) {
    __shared__ double red[N_COLS];
    int t = threadIdx.x;
    red[t] = col_corr[t];
    __syncthreads();
    for (int off = N_COLS / 2; off > 0; off >>= 1) {
        if (t < off) red[t] += red[t + off];
        __syncthreads();
    }
    if (t == 0) out[0] = (float)(-red[0] / (double)N_COLS);
}

extern "C" void kernel_launch(void* const* d_in, const int* in_sizes, int n_in,
                              void* d_out, int out_size, void* d_ws, size_t ws_size,
                              hipStream_t stream) {
    const float* pred   = (const float*)d_in[0];
    const float* target = (const float*)d_in[1];
    float* out = (float*)d_out;

    const size_t mat_bytes = (size_t)N_ROWS * N_COLS * sizeof(float);
    double* col_corr = (double*)d_ws;                       // 4 KB
    float* predT   = (float*)((char*)d_ws + 65536);
    float* targetT = predT + (size_t)N_ROWS * N_COLS;
    const size_t need = 65536 + 2 * mat_bytes;

    if (ws_size >= need) {
        dim3 tgrid(N_ROWS / 64, N_COLS / 64, 2);
        transpose_kernel<<<tgrid, 256, 0, stream>>>(pred, target, predT, targetT);
        spearman_col_kernel<1><<<N_COLS, NT, 0, stream>>>(predT, targetT, col_corr);
    } else {
        spearman_col_kernel<0><<<N_COLS, NT, 0, stream>>>(pred, target, col_corr);
    }
    finalize_kernel<<<1, N_COLS, 0, stream>>>(col_corr, out);
}